// Round 11
// baseline (485.816 us; speedup 1.0000x reference)
//
#include <hip/hip_runtime.h>
#include <hip/hip_bf16.h>

typedef __hip_bfloat16 bf16;
typedef __attribute__((ext_vector_type(8))) short bf16x8;
typedef __attribute__((ext_vector_type(4))) short s16x4;
typedef __attribute__((ext_vector_type(4))) float f32x4;
typedef __attribute__((ext_vector_type(16))) float f32x16;
typedef __attribute__((ext_vector_type(2))) unsigned int u32x2;
typedef __attribute__((ext_vector_type(4))) unsigned int u32x4;

__device__ __forceinline__ float b2f(bf16 v) { return __bfloat162float(v); }
__device__ __forceinline__ bf16  f2b(float v) { return __float2bfloat16(v); }
__device__ __forceinline__ float ldf(const bf16* p)  { return __bfloat162float(*p); }
__device__ __forceinline__ float ldf(const float* p) { return *p; }
__device__ __forceinline__ void  stf(bf16* p, float v)  { *p = __float2bfloat16(v); }
__device__ __forceinline__ void  stf(float* p, float v) { *p = v; }

// HW packed f32x2 -> bf16x2 convert (RNE). No builtin on gfx950 (T12 recipe).
__device__ __forceinline__ unsigned cvt_pk_bf16(float lo, float hi) {
    unsigned r;
    asm("v_cvt_pk_bf16_f32 %0, %1, %2" : "=v"(r) : "v"(lo), "v"(hi));
    return r;
}

// vectorized 4-element row loads for LayerNorm
__device__ __forceinline__ void ld4(const float* p, float* v) {
    float4 t = *(const float4*)p;
    v[0] = t.x; v[1] = t.y; v[2] = t.z; v[3] = t.w;
}
__device__ __forceinline__ void ld4(const bf16* p, float* v) {
    s16x4 t = *(const s16x4*)p;
#pragma unroll
    for (int j = 0; j < 4; ++j) { short s = t[j]; v[j] = b2f(*(bf16*)&s); }
}

// async global->LDS, 16 B per lane; LDS dest = wave-uniform base + lane*16
__device__ __forceinline__ void load_lds16(const bf16* g, short* lds) {
    __builtin_amdgcn_global_load_lds(
        (const __attribute__((address_space(1))) unsigned int*)g,
        (__attribute__((address_space(3))) unsigned int*)lds, 16, 0, 0);
}

// ---------------------------------------------------------------------------
// LayerNorm over last dim C=1024. One block (256 threads) per row. bf16 out.
// ---------------------------------------------------------------------------
template<typename InT>
__global__ __launch_bounds__(256) void ln_kernel(const InT* __restrict__ x,
                                                 const float* __restrict__ g,
                                                 const float* __restrict__ b,
                                                 bf16* __restrict__ out)
{
    const int C = 1024;
    int row = blockIdx.x;
    int tid = threadIdx.x;
    const InT* xr = x + (size_t)row * C;

    float v[4];
    ld4(xr + tid * 4, v);
    float s = 0.f, s2 = 0.f;
#pragma unroll
    for (int i = 0; i < 4; ++i) { s += v[i]; s2 += v[i] * v[i]; }
#pragma unroll
    for (int off = 32; off > 0; off >>= 1) {
        s  += __shfl_down(s,  off, 64);
        s2 += __shfl_down(s2, off, 64);
    }
    __shared__ float red[8];
    int wave = tid >> 6;
    if ((tid & 63) == 0) { red[wave] = s; red[wave + 4] = s2; }
    __syncthreads();
    float ts  = red[0] + red[1] + red[2] + red[3];
    float ts2 = red[4] + red[5] + red[6] + red[7];
    float mu  = ts * (1.f / 1024.f);
    float var = ts2 * (1.f / 1024.f) - mu * mu;
    float rstd = rsqrtf(var + 1e-5f);

    float4 gg = *(const float4*)(g + tid * 4);
    float4 bb = *(const float4*)(b + tid * 4);
    float gj[4] = {gg.x, gg.y, gg.z, gg.w};
    float bj[4] = {bb.x, bb.y, bb.z, bb.w};
    s16x4 o4;
#pragma unroll
    for (int j = 0; j < 4; ++j) {
        bf16 ob = f2b((v[j] - mu) * rstd * gj[j] + bj[j]);
        o4[j] = *(short*)&ob;
    }
    *(s16x4*)(out + (size_t)row * C + tid * 4) = o4;
}

// ---------------------------------------------------------------------------
// All six weight transposes (fp32 -> bf16, out[n][k] = in[k][n]) in ONE
// kernel. Flat tile id selects matrix + 32x32 tile.
// ---------------------------------------------------------------------------
__global__ __launch_bounds__(256) void prep_weights(
    const float* __restrict__ Wq, const float* __restrict__ Wk,
    const float* __restrict__ Wv, const float* __restrict__ Wo,
    const float* __restrict__ W1, const float* __restrict__ W2,
    bf16* __restrict__ wqkvt, bf16* __restrict__ wot,
    bf16* __restrict__ w1t, bf16* __restrict__ w2t)
{
    __shared__ float t[32][33];
    int tx = threadIdx.x & 31, ty = threadIdx.x >> 5;
    int id = blockIdx.x;
    const float* in; bf16* out; int in_ld, out_ld, n0, k0;
    if (id < 3072) {
        const float* Ws[3] = {Wq, Wk, Wv};
        int m = id >> 10, r = id & 1023;
        int z = r >> 6, rt = r & 63;
        in = Ws[m] + z * 65536;                       // [1024][64]
        out = wqkvt + (size_t)(m * 1024 + z * 64) * 1024;
        in_ld = 64; out_ld = 1024;
        n0 = (rt & 1) * 32; k0 = (rt >> 1) * 32;
    } else if (id < 4096) {
        int r = id - 3072;
        in = Wo; out = wot; in_ld = 1024; out_ld = 1024;
        n0 = (r & 31) * 32; k0 = (r >> 5) * 32;
    } else if (id < 8192) {
        int r = id - 4096;
        in = W1; out = w1t; in_ld = 4096; out_ld = 1024;
        n0 = (r & 127) * 32; k0 = (r >> 7) * 32;
    } else {
        int r = id - 8192;
        in = W2; out = w2t; in_ld = 1024; out_ld = 4096;
        n0 = (r & 31) * 32; k0 = (r >> 5) * 32;
    }
#pragma unroll
    for (int i = 0; i < 4; ++i)
        t[ty + i * 8][tx] = in[(size_t)(k0 + ty + i * 8) * in_ld + n0 + tx];
    __syncthreads();
#pragma unroll
    for (int i = 0; i < 4; ++i)
        out[(size_t)(n0 + ty + i * 8) * out_ld + k0 + tx] = f2b(t[tx][ty + i * 8]);
}

// ---------------------------------------------------------------------------
// V^T: vt[(b*16+h)*64 + d][t] = qkv[(b*T+t)*3072 + 2048 + h*64 + d]
// ---------------------------------------------------------------------------
__global__ __launch_bounds__(256) void vt_kernel(
    const bf16* __restrict__ qkv, bf16* __restrict__ vt, int T)
{
    __shared__ float t[32][33];
    int tx = threadIdx.x & 31, ty = threadIdx.x >> 5;
    int z = blockIdx.z, b = z >> 4, h = z & 15;
    const bf16* in = qkv + (size_t)b * T * 3072 + 2048 + h * 64;  // [t][d] ld 3072
    bf16* out = vt + (size_t)z * 64 * T;                          // [d][t] ld T
    int n0 = blockIdx.x * 32, k0 = blockIdx.y * 32;
#pragma unroll
    for (int i = 0; i < 4; ++i)
        t[ty + i * 8][tx] = b2f(in[(size_t)(k0 + ty + i * 8) * 3072 + n0 + tx]);
    __syncthreads();
#pragma unroll
    for (int i = 0; i < 4; ++i)
        out[(size_t)(n0 + ty + i * 8) * T + k0 + tx] = f2b(t[tx][ty + i * 8]);
}

// ---------------------------------------------------------------------------
// 256x256 MFMA GEMM (T2+T3+T4+T5), plain HIP. 512 thr = 8 waves.
// R6-verified body (82.8 us FFN1, MfmaUtil 33.5). BK=32, FOUR LDS buffers
// (128 KB), staging 3 tiles ahead alias-free. 2 phases/K-tile, ds_reads
// balanced 8/4; counted vmcnt never 0 in steady state; 0-conflict swizzle.
// Requires: M%256==0, N%256==0, K%32==0, K/32>=4, grid %8==0.
// ---------------------------------------------------------------------------
template<bool RELU, bool HAS_BIAS, typename OutT>
__global__ __launch_bounds__(512, 2) void gemm8p(
    const bf16* __restrict__ A, int lda,
    const bf16* __restrict__ Bt, int ldb,
    const float* __restrict__ bias,
    OutT* __restrict__ Cm, int ldc,
    int M, int N, int K)
{
    __shared__ short As[4][8192];
    __shared__ short Bs[4][8192];
    int tid = threadIdx.x, wv = tid >> 6, ln = tid & 63;
    int quad = ln >> 4, lane15 = ln & 15;

    // XCD-chunked bijective remap (nwg % 8 == 0)
    int nbn = N >> 8;
    int nwg = gridDim.x;
    int f2 = (blockIdx.x & 7) * (nwg >> 3) + (blockIdx.x >> 3);
    int by = f2 / nbn, bx = f2 % nbn;
    int bm0 = by << 8, bn0 = bx << 8;

    int wr = wv >> 2, wc = wv & 3;     // wave row-half / col-quarter
    const int NT = K >> 5;

    // staging addresses (per thread); linear LDS dest, swizzled source
    int sr = tid >> 2;                                  // row 0..127
    int sc = ((tid & 3) ^ ((sr >> 1) & 3)) * 8;
    const bf16* Ab1 = A  + (size_t)(bm0 + sr) * lda + sc;
    const bf16* Ab2 = A  + (size_t)(bm0 + 128 + sr) * lda + sc;
    const bf16* Bb1 = Bt + (size_t)(bn0 + sr) * ldb + sc;
    const bf16* Bb2 = Bt + (size_t)(bn0 + 128 + sr) * ldb + sc;

#define STAGE_A8(bf_, u_) { \
    load_lds16(Ab1 + (u_) * 32, &As[bf_][wv * 512]); \
    load_lds16(Ab2 + (u_) * 32, &As[bf_][4096 + wv * 512]); }
#define STAGE_B8(bf_, u_) { \
    load_lds16(Bb1 + (u_) * 32, &Bs[bf_][wv * 512]); \
    load_lds16(Bb2 + (u_) * 32, &Bs[bf_][4096 + wv * 512]); }

    f32x4 acc[8][4] = {};                 // 128 VGPRs
    int arow = wr * 128 + lane15;
    int brow = wc * 64 + lane15;
    int sw = (quad ^ ((lane15 >> 1) & 3)) * 8;

    // prologue: stage tiles 0,1,2; wait tile 0 (8 loads stay in flight)
    STAGE_A8(0, 0); STAGE_B8(0, 0);
    STAGE_A8(1, 1); STAGE_B8(1, 1);
    STAGE_A8(2, 2); STAGE_B8(2, 2);
    asm volatile("s_waitcnt vmcnt(8)" ::: "memory");
    __builtin_amdgcn_s_barrier();

    for (int t = 0; t < NT; ++t) {
        int buf = t & 3;
        const short* Al = &As[buf][0];
        const short* Bl = &Bs[buf][0];

        // ---- phase 0: af[0..3] + bf[0..3]; stage A(t+3)
        bf16x8 af[4], bfr[4];
#pragma unroll
        for (int mi = 0; mi < 4; ++mi)
            af[mi] = *(const bf16x8*)&Al[(arow + mi * 16) * 32 + sw];
#pragma unroll
        for (int ni = 0; ni < 4; ++ni)
            bfr[ni] = *(const bf16x8*)&Bl[(brow + ni * 16) * 32 + sw];
        if (t + 3 < NT) STAGE_A8((t + 3) & 3, t + 3);
        __builtin_amdgcn_s_barrier();
        __builtin_amdgcn_s_setprio(1);
#pragma unroll
        for (int mi = 0; mi < 4; ++mi)
#pragma unroll
            for (int ni = 0; ni < 4; ++ni)
                acc[mi][ni] = __builtin_amdgcn_mfma_f32_16x16x32_bf16(
                    af[mi], bfr[ni], acc[mi][ni], 0, 0, 0);
        __builtin_amdgcn_s_setprio(0);
        __builtin_amdgcn_s_barrier();

        // ---- phase 1: af[4..7] (bf in regs); stage B(t+3); counted wait
        bf16x8 ag[4];
#pragma unroll
        for (int mi = 0; mi < 4; ++mi)
            ag[mi] = *(const bf16x8*)&Al[(arow + (mi + 4) * 16) * 32 + sw];
        if (t + 3 < NT) STAGE_B8((t + 3) & 3, t + 3);
        if (t < NT - 3) {
            asm volatile("s_waitcnt vmcnt(8)" ::: "memory");   // tile t+1 landed
        } else if (t == NT - 3) {
            asm volatile("s_waitcnt vmcnt(4)" ::: "memory");
        } else if (t == NT - 2) {
            asm volatile("s_waitcnt vmcnt(0)" ::: "memory");   // tail only
        }
        __builtin_amdgcn_s_barrier();
        __builtin_amdgcn_s_setprio(1);
#pragma unroll
        for (int mi = 0; mi < 4; ++mi)
#pragma unroll
            for (int ni = 0; ni < 4; ++ni)
                acc[mi + 4][ni] = __builtin_amdgcn_mfma_f32_16x16x32_bf16(
                    ag[mi], bfr[ni], acc[mi + 4][ni], 0, 0, 0);
        __builtin_amdgcn_s_setprio(0);
        __builtin_amdgcn_s_barrier();
    }

#undef STAGE_A8
#undef STAGE_B8

    // ---- epilogue
#pragma unroll
    for (int mi = 0; mi < 8; ++mi) {
#pragma unroll
        for (int r = 0; r < 4; ++r) {
            int gm = bm0 + wr * 128 + mi * 16 + quad * 4 + r;
#pragma unroll
            for (int ni = 0; ni < 4; ++ni) {
                int gn = bn0 + wc * 64 + ni * 16 + lane15;
                float v = acc[mi][ni][r];
                if (HAS_BIAS) v += bias[gn];
                if (RELU)     v = fmaxf(v, 0.f);
                stf(Cm + (size_t)gm * ldc + gn, v);
            }
        }
    }
}

// ---------------------------------------------------------------------------
// MFMA GEMM: C[M,N] = A[M,K] @ B[K,N], B given TRANSPOSED (Bt[n][k]).
// 128x128 tile, 256 thr = 4 waves, templated BK (32 or 64). Double-buffered
// LDS, stage-before-compute, one __syncthreads per K-step. Used for the
// N=1024 GEMMs (Wo, FFN2) where 256-wide col tiles would underfill the grid.
// ---------------------------------------------------------------------------
template<int BK, bool RELU, bool HAS_BIAS, bool HAS_RES, typename ResT, typename OutT>
__global__ __launch_bounds__(256) void gemm_bt(
    const bf16* __restrict__ A, int lda,
    const bf16* __restrict__ Bt, int ldb,
    const float* __restrict__ bias,
    const ResT* __restrict__ res, int ldr,
    OutT* __restrict__ Cm, int ldc,
    int M, int N, int K)
{
    __shared__ short As[2][128 * BK];
    __shared__ short Bs[2][128 * BK];
    int tid = threadIdx.x, wv = tid >> 6, ln = tid & 63;

    int f = blockIdx.x + blockIdx.y * gridDim.x;
    int nby = gridDim.y;
    int by = f % nby, bx = f / nby;
    int bm0 = by * 128, bn0 = bx * 128;

    int wm = (wv & 1) * 64, wn = (wv >> 1) * 64;
    int quad = ln >> 4, lane15 = ln & 15;

    f32x4 acc[4][4] = {};

    const bf16* Ab = A + (size_t)bm0 * lda;
    const bf16* Bb = Bt + (size_t)bn0 * ldb;

    auto stage = [&](int buf, int kk) {
        if constexpr (BK == 32) {
            int srow = ln >> 2;
            int scol = (((ln & 3) ^ ((ln >> 3) & 3)) * 8);
#pragma unroll
            for (int i = 0; i < 2; ++i) {
                int ch = wv + i * 4;
                load_lds16(Ab + (size_t)(ch * 16 + srow) * lda + kk + scol,
                           &As[buf][ch * 16 * 32]);
                load_lds16(Bb + (size_t)(ch * 16 + srow) * ldb + kk + scol,
                           &Bs[buf][ch * 16 * 32]);
            }
        } else {
            int srow = ln >> 3;
            int scol = ((ln & 7) ^ srow) * 8;
#pragma unroll
            for (int i = 0; i < 4; ++i) {
                int r0 = i * 32 + wv * 8;
                load_lds16(Ab + (size_t)(r0 + srow) * lda + kk + scol,
                           &As[buf][r0 * 64]);
                load_lds16(Bb + (size_t)(r0 + srow) * ldb + kk + scol,
                           &Bs[buf][r0 * 64]);
            }
        }
    };

    stage(0, 0);
    __syncthreads();

    int cur = 0;
    for (int k0 = 0; k0 < K; k0 += BK) {
        if (k0 + BK < K) stage(cur ^ 1, k0 + BK);
        if constexpr (BK == 32) {
            int sw = (quad ^ ((lane15 >> 1) & 3)) * 8;
            bf16x8 af[4], bfr[4];
#pragma unroll
            for (int mi = 0; mi < 4; ++mi)
                af[mi] = *(const bf16x8*)&As[cur][(wm + mi * 16 + lane15) * 32 + sw];
#pragma unroll
            for (int ni = 0; ni < 4; ++ni)
                bfr[ni] = *(const bf16x8*)&Bs[cur][(wn + ni * 16 + lane15) * 32 + sw];
#pragma unroll
            for (int mi = 0; mi < 4; ++mi)
#pragma unroll
                for (int ni = 0; ni < 4; ++ni)
                    acc[mi][ni] = __builtin_amdgcn_mfma_f32_16x16x32_bf16(
                        af[mi], bfr[ni], acc[mi][ni], 0, 0, 0);
        } else {
#pragma unroll
            for (int ks = 0; ks < 2; ++ks) {
                int sw = (((ks * 4 + quad) ^ (lane15 & 7)) * 8);
                bf16x8 af[4], bfr[4];
#pragma unroll
                for (int mi = 0; mi < 4; ++mi)
                    af[mi] = *(const bf16x8*)&As[cur][(wm + mi * 16 + lane15) * 64 + sw];
#pragma unroll
                for (int ni = 0; ni < 4; ++ni)
                    bfr[ni] = *(const bf16x8*)&Bs[cur][(wn + ni * 16 + lane15) * 64 + sw];
#pragma unroll
                for (int mi = 0; mi < 4; ++mi)
#pragma unroll
                    for (int ni = 0; ni < 4; ++ni)
                        acc[mi][ni] = __builtin_amdgcn_mfma_f32_16x16x32_bf16(
                            af[mi], bfr[ni], acc[mi][ni], 0, 0, 0);
            }
        }
        __syncthreads();
        cur ^= 1;
    }

#pragma unroll
    for (int mi = 0; mi < 4; ++mi) {
#pragma unroll
        for (int r = 0; r < 4; ++r) {
            int gm = bm0 + wm + mi * 16 + quad * 4 + r;
#pragma unroll
            for (int ni = 0; ni < 4; ++ni) {
                int gn = bn0 + wn + ni * 16 + lane15;
                float v = acc[mi][ni][r];
                if (HAS_BIAS) v += bias[gn];
                if (HAS_RES)  v += ldf(res + (size_t)gm * ldr + gn);
                if (RELU)     v = fmaxf(v, 0.f);
                stf(Cm + (size_t)gm * ldc + gn, v);
            }
        }
    }
}

// ---------------------------------------------------------------------------
// 32x32x16 attention tile step. S^T = mfma(K, Q): lane holds
// S^T[key = (r&3)+8*(r>>2)+4*hi + ts*32][q = lane&31] (verified C/D map).
// Constant-shift softmax (exp2 domain, no running max). P^T B-fragment for
// PV built IN-REGISTER: 4 cvt_pk + 2 permlane32_swap per 16-key slice
// (lane half hi holds keys {0..3,8..11,16..19,24..27}+4hi; swap(w0,w2) and
// (w1,w3) reassemble k-contiguous words for both halves). No P LDS traffic.
// DUAL: shared kf/vf reads feed both q-tiles; mask applies to b only
// (kb+63 <= qa_min for all dual-active tiles, checked for all bx).
// ---------------------------------------------------------------------------
template<bool DUAL>
__device__ __forceinline__ void attn_tile32(
    const short* __restrict__ Ks, const short* __restrict__ Vs,
    const bf16x8* qfa, const bf16x8* qfb,
    f32x16* oa, f32x16* ob, float& lra, float& lrb,
    int kb, int qmina, int qminb, int l31, int hi, int l7)
{
    const float scale2 = 0.18033688011112042f;   // (1/8) * log2(e)
    f32x16 sa[2] = {};
    f32x16 sb[2] = {};

    __builtin_amdgcn_s_setprio(1);
#pragma unroll
    for (int ts = 0; ts < 2; ++ts) {
#pragma unroll
        for (int ks = 0; ks < 4; ++ks) {
            bf16x8 kf = *(const bf16x8*)&Ks[(ts * 32 + l31) * 64 + (((ks * 2 + hi) ^ l7) * 8)];
            sa[ts] = __builtin_amdgcn_mfma_f32_32x32x16_bf16(kf, qfa[ks], sa[ts], 0, 0, 0);
            if (DUAL)
                sb[ts] = __builtin_amdgcn_mfma_f32_32x32x16_bf16(kf, qfb[ks], sb[ts], 0, 0, 0);
        }
    }
    __builtin_amdgcn_s_setprio(0);

    // causal mask (fused path masks b; single path masks a)
    int qmin = DUAL ? qminb : qmina;
    if (kb + 63 > qmin) {
        int qcap = qmin + l31;
#pragma unroll
        for (int ts = 0; ts < 2; ++ts)
#pragma unroll
            for (int r = 0; r < 16; ++r) {
                int key = kb + ts * 32 + (r & 3) + 8 * (r >> 2) + 4 * hi;
                if (key > qcap) {
                    if (DUAL) sb[ts][r] = -3e38f; else sa[ts][r] = -3e38f;
                }
            }
    }

    // exp2 in place + row-partial sums (lane holds 32 of 64 keys for q=l31)
    float psa = 0.f, psb = 0.f;
#pragma unroll
    for (int ts = 0; ts < 2; ++ts)
#pragma unroll
        for (int r = 0; r < 16; ++r) {
            float va = exp2f(sa[ts][r] * scale2);
            sa[ts][r] = va; psa += va;
            if (DUAL) {
                float vb = exp2f(sb[ts][r] * scale2);
                sb[ts][r] = vb; psb += vb;
            }
        }
    lra += psa;
    if (DUAL) lrb += psb;

    // PV: per 16-key slice s build P^T frag in-register, MFMA vs V^T
    __builtin_amdgcn_s_setprio(1);
#pragma unroll
    for (int s = 0; s < 4; ++s) {
        const int ts = s >> 1, q0 = (s & 1) * 8;
        unsigned a0 = cvt_pk_bf16(sa[ts][q0 + 0], sa[ts][q0 + 1]);
        unsigned a1 = cvt_pk_bf16(sa[ts][q0 + 2], sa[ts][q0 + 3]);
        unsigned a2 = cvt_pk_bf16(sa[ts][q0 + 4], sa[ts][q0 + 5]);
        unsigned a3 = cvt_pk_bf16(sa[ts][q0 + 6], sa[ts][q0 + 7]);
        u32x2 s02 = __builtin_amdgcn_permlane32_swap(a0, a2, false, false);
        u32x2 s13 = __builtin_amdgcn_permlane32_swap(a1, a3, false, false);
        u32x4 fa = {s02[0], s13[0], s02[1], s13[1]};
        bf16x8 pfa = *(bf16x8*)&fa;
        bf16x8 pfb;
        if (DUAL) {
            unsigned b0 = cvt_pk_bf16(sb[ts][q0 + 0], sb[ts][q0 + 1]);
            unsigned b1 = cvt_pk_bf16(sb[ts][q0 + 2], sb[ts][q0 + 3]);
            unsigned b2 = cvt_pk_bf16(sb[ts][q0 + 4], sb[ts][q0 + 5]);
            unsigned b3 = cvt_pk_bf16(sb[ts][q0 + 6], sb[ts][q0 + 7]);
            u32x2 t02 = __builtin_amdgcn_permlane32_swap(b0, b2, false, false);
            u32x2 t13 = __builtin_amdgcn_permlane32_swap(b1, b3, false, false);
            u32x4 fb = {t02[0], t13[0], t02[1], t13[1]};
            pfb = *(bf16x8*)&fb;
        }
#pragma unroll
        for (int dt = 0; dt < 2; ++dt) {
            bf16x8 vf = *(const bf16x8*)&Vs[(dt * 32 + l31) * 64 + (((s * 2 + hi) ^ l7) * 8)];
            oa[dt] = __builtin_amdgcn_mfma_f32_32x32x16_bf16(vf, pfa, oa[dt], 0, 0, 0);
            if (DUAL)
                ob[dt] = __builtin_amdgcn_mfma_f32_32x32x16_bf16(vf, pfb, ob[dt], 0, 0, 0);
        }
    }
    __builtin_amdgcn_s_setprio(0);
}

// ---------------------------------------------------------------------------
// MFMA causal flash attention, 32x32x16 form, 512 thr = 8 waves x 32 q-rows
// (256-row q-tile). CAUSAL-BALANCED DUAL Q-TILE: block bx processes q-tiles
// (7-bx, bx) in ONE k-loop sharing K/V staging AND fragment reads. Uniform
// 36 kv-tile-units/block; grid 256 = 1 block/CU, all co-resident.
// Q fragments loaded directly from global (once). O^T accumulated in regs;
// P never touches LDS. K/V double-buffered in LDS (slot ^= row&7 swizzle).
// ---------------------------------------------------------------------------
__global__ __launch_bounds__(512, 2) void attn_kernel(
    const bf16* __restrict__ qkv, const bf16* __restrict__ vt,
    bf16* __restrict__ o, int T)
{
    const int LDQ = 3072;
    int bx = blockIdx.x;             // 0..3
    int qta = 7 - bx;                // heavy q-tile (256 rows)
    int qtb = bx;                    // light q-tile
    int h = blockIdx.y, b = blockIdx.z;
    int tid = threadIdx.x, wv = tid >> 6, ln = tid & 63;
    int l31 = ln & 31, hi = ln >> 5, l7 = ln & 7;

    __shared__ short KV[2][2][64 * 64];   // [buf][0=K [key][d], 1=V [d][key]]

    int lr = ln >> 3;                     // staging row within 8-row chunk
    int lc = ((ln & 7) ^ lr) * 8;         // swizzled source col offset

    const bf16* kbase = qkv + (size_t)(b * T) * LDQ + 1024 + h * 64;
    const bf16* vbase = vt + (size_t)((b * 16 + h) * 64) * T;

    // ---- Q fragments straight from global (once per block)
    bf16x8 qfa[4], qfb[4];
    {
        const bf16* qa = qkv + (size_t)(b * T + qta * 256 + wv * 32 + l31) * LDQ + h * 64 + hi * 8;
        const bf16* qb = qkv + (size_t)(b * T + qtb * 256 + wv * 32 + l31) * LDQ + h * 64 + hi * 8;
#pragma unroll
        for (int ks = 0; ks < 4; ++ks) {
            qfa[ks] = *(const bf16x8*)(qa + ks * 16);
            qfb[ks] = *(const bf16x8*)(qb + ks * 16);
        }
    }

    f32x16 oa[2] = {}, ob[2] = {};
    float lra = 0.f, lrb = 0.f;
    int qmina = qta * 256 + wv * 32;
    int qminb = qtb * 256 + wv * 32;
    int ntiles = (qta + 1) * 4;

    // stage tile 0 into buf 0 (wave wv stages rows wv*8..wv*8+7)
    const bf16* kp = kbase + (size_t)(wv * 8 + lr) * LDQ + lc;
    const bf16* vp = vbase + (size_t)(wv * 8 + lr) * T + lc;
    load_lds16(kp, &KV[0][0][wv * 8 * 64]);
    load_lds16(vp, &KV[0][1][wv * 8 * 64]);

    for (int kt = 0; kt < ntiles; ++kt) {
        __syncthreads();   // tile kt published (barrier drains vmcnt)
        if (kt + 1 < ntiles) {
            int nb = (kt + 1) & 1;
            kp += 64 * LDQ;
            vp += 64;
            load_lds16(kp, &KV[nb][0][wv * 8 * 64]);
            load_lds16(vp, &KV[nb][1][wv * 8 * 64]);
        }
        const short* Ks = &KV[kt & 1][0][0];
        const short* Vs = &KV[kt & 1][1][0];
        int kb = kt * 64;

        if (kb <= qminb + 31)
            attn_tile32<true>(Ks, Vs, qfa, qfb, oa, ob, lra, lrb,
                              kb, qmina, qminb, l31, hi, l7);
        else if (kb <= qmina + 31)
            attn_tile32<false>(Ks, Vs, qfa, qfb, oa, ob, lra, lrb,
                               kb, qmina, qminb, l31, hi, l7);
    }

    // ---- epilogue: cross-half l reduce + store. O^T reg layout:
    // value (d_local = (r&3)+8*(r>>2)+4*hi + dt*32, q = l31).
    lra += __shfl_xor(lra, 32, 64);
    float inva = 1.f / lra;
    size_t rowa = (size_t)(b * T + qta * 256 + wv * 32 + l31);
#pragma unroll
    for (int dt = 0; dt < 2; ++dt)
#pragma unroll
        for (int rq = 0; rq < 4; ++rq) {
            u32x2 ou;
            ou[0] = cvt_pk_bf16(oa[dt][rq * 4 + 0] * inva, oa[dt][rq * 4 + 1] * inva);
            ou[1] = cvt_pk_bf16(oa[dt][rq * 4 + 2] * inva, oa[dt][rq * 4 + 3] * inva);
            *(u32x2*)&o[rowa * 1024 + h * 64 + dt * 32 + rq * 8 + hi * 4] = ou;
        }

    lrb += __shfl_xor(lrb, 32, 64);
    float invb = 1.f / lrb;
    size_t rowb = (size_t)(b * T + qtb * 256 + wv * 32 + l31);
#pragma unroll
    for (int dt = 0; dt < 2; ++dt)
#pragma unroll
        for (int rq = 0; rq < 4; ++rq) {
            u32x2 ou;
            ou[0] = cvt_pk_bf16(ob[dt][rq * 4 + 0] * invb, ob[dt][rq * 4 + 1] * invb);
            ou[1] = cvt_pk_bf16(ob[dt][rq * 4 + 2] * invb, ob[dt][rq * 4 + 3] * invb);
            *(u32x2*)&o[rowb * 1024 + h * 64 + dt * 32 + rq * 8 + hi * 4] = ou;
        }
}

// ---------------------------------------------------------------------------
extern "C" void kernel_launch(void* const* d_in, const int* in_sizes, int n_in,
                              void* d_out, int out_size, void* d_ws, size_t ws_size,
                              hipStream_t stream)
{
    (void)in_sizes; (void)n_in; (void)out_size; (void)ws_size;
    const float* x   = (const float*)d_in[0];
    const float* Wq  = (const float*)d_in[1];
    const float* Wk  = (const float*)d_in[2];
    const float* Wv  = (const float*)d_in[3];
    const float* Wo  = (const float*)d_in[4];
    const float* bo  = (const float*)d_in[5];
    const float* g1  = (const float*)d_in[6];
    const float* be1 = (const float*)d_in[7];
    const float* g2  = (const float*)d_in[8];
    const float* be2 = (const float*)d_in[9];
    const float* W1  = (const float*)d_in[10];
    const float* b1  = (const float*)d_in[11];
    const float* W2  = (const float*)d_in[12];
    const float* b2  = (const float*)d_in[13];

    const int T = 2048, M = 4 * T;  // 8192 rows
    const size_t MB = 1ull << 20;
    char* ws = (char*)d_ws;

    // workspace map (128 MB, live-range overlays):
    bf16*  xn    = (bf16*)(ws + 0 * MB);     // 16 MB; later: attnb; later: hb
    bf16*  qkv   = (bf16*)(ws + 16 * MB);    // 48 MB [M][3072]; later: hb tail
    bf16*  vt    = (bf16*)(ws + 64 * MB);    // 16 MB [b*16+h][64][T]
    bf16*  wqkvt = (bf16*)(ws + 80 * MB);    //  6 MB [3072][1024]; later: x1b
    bf16*  x1b   = (bf16*)(ws + 80 * MB);    // 16 MB [M][1024] bf16 residual
    bf16*  wot   = (bf16*)(ws + 96 * MB);    //  2 MB; later: xn2
    bf16*  xn2   = (bf16*)(ws + 96 * MB);    // 16 MB
    bf16*  w1t   = (bf16*)(ws + 112 * MB);   //  8 MB [4096][1024]
    bf16*  w2t   = (bf16*)(ws + 120 * MB);   //  8 MB [1024][4096]
    bf16*  attnb = (bf16*)(ws + 0 * MB);
    bf16*  hb    = (bf16*)(ws + 0 * MB);     // 64 MB [M][4096]

    dim3 blk(256);

    prep_weights<<<12288, blk, 0, stream>>>(Wq, Wk, Wv, Wo, W1, W2,
                                            wqkvt, wot, w1t, w2t);

    ln_kernel<float><<<M, blk, 0, stream>>>(x, g1, be1, xn);

    // QKV: 256^2 8-phase, grid 32x12 = 384
    gemm8p<false, false, bf16><<<dim3(384), dim3(512), 0, stream>>>(
        xn, 1024, wqkvt, 1024, nullptr, qkv, 3072, M, 3072, 1024);

    vt_kernel<<<dim3(2, T / 32, 64), blk, 0, stream>>>(qkv, vt, T);

    attn_kernel<<<dim3(4, 16, 4), dim3(512), 0, stream>>>(qkv, vt, attnb, T);

    gemm_bt<32, false, true, true, float, bf16><<<dim3(8, 64), blk, 0, stream>>>(
        attnb, 1024, wot, 1024, bo, x, 1024, x1b, 1024, M, 1024, 1024);

    ln_kernel<bf16><<<M, blk, 0, stream>>>(x1b, g2, be2, xn2);

    // FFN1: 256^2 8-phase, grid 32x16 = 512
    gemm8p<true, true, bf16><<<dim3(512), dim3(512), 0, stream>>>(
        xn2, 1024, w1t, 1024, b1, hb, 4096, M, 4096, 1024);

    gemm_bt<64, false, true, true, bf16, float><<<dim3(8, 64), blk, 0, stream>>>(
        hb, 4096, w2t, 4096, b2, x1b, 1024, (float*)d_out, 1024, M, 1024, 4096);
}

// Round 12
// 472.677 us; speedup vs baseline: 1.0278x; 1.0278x over previous
//
#include <hip/hip_runtime.h>
#include <hip/hip_bf16.h>

typedef __hip_bfloat16 bf16;
typedef __attribute__((ext_vector_type(8))) short bf16x8;
typedef __attribute__((ext_vector_type(4))) short s16x4;
typedef __attribute__((ext_vector_type(4))) float f32x4;
typedef __attribute__((ext_vector_type(16))) float f32x16;
typedef __attribute__((ext_vector_type(2))) unsigned int u32x2;
typedef __attribute__((ext_vector_type(4))) unsigned int u32x4;

__device__ __forceinline__ float b2f(bf16 v) { return __bfloat162float(v); }
__device__ __forceinline__ bf16  f2b(float v) { return __float2bfloat16(v); }
__device__ __forceinline__ float ldf(const bf16* p)  { return __bfloat162float(*p); }
__device__ __forceinline__ float ldf(const float* p) { return *p; }
__device__ __forceinline__ void  stf(bf16* p, float v)  { *p = __float2bfloat16(v); }
__device__ __forceinline__ void  stf(float* p, float v) { *p = v; }

// HW packed f32x2 -> bf16x2 convert (RNE). No builtin on gfx950 (T12 recipe).
__device__ __forceinline__ unsigned cvt_pk_bf16(float lo, float hi) {
    unsigned r;
    asm("v_cvt_pk_bf16_f32 %0, %1, %2" : "=v"(r) : "v"(lo), "v"(hi));
    return r;
}

// vectorized 4-element row loads for LayerNorm
__device__ __forceinline__ void ld4(const float* p, float* v) {
    float4 t = *(const float4*)p;
    v[0] = t.x; v[1] = t.y; v[2] = t.z; v[3] = t.w;
}
__device__ __forceinline__ void ld4(const bf16* p, float* v) {
    s16x4 t = *(const s16x4*)p;
#pragma unroll
    for (int j = 0; j < 4; ++j) { short s = t[j]; v[j] = b2f(*(bf16*)&s); }
}

// async global->LDS, 16 B per lane; LDS dest = wave-uniform base + lane*16
__device__ __forceinline__ void load_lds16(const bf16* g, short* lds) {
    __builtin_amdgcn_global_load_lds(
        (const __attribute__((address_space(1))) unsigned int*)g,
        (__attribute__((address_space(3))) unsigned int*)lds, 16, 0, 0);
}

// ---------------------------------------------------------------------------
// LayerNorm over last dim C=1024. One block (256 threads) per row. bf16 out.
// ---------------------------------------------------------------------------
template<typename InT>
__global__ __launch_bounds__(256) void ln_kernel(const InT* __restrict__ x,
                                                 const float* __restrict__ g,
                                                 const float* __restrict__ b,
                                                 bf16* __restrict__ out)
{
    const int C = 1024;
    int row = blockIdx.x;
    int tid = threadIdx.x;
    const InT* xr = x + (size_t)row * C;

    float v[4];
    ld4(xr + tid * 4, v);
    float s = 0.f, s2 = 0.f;
#pragma unroll
    for (int i = 0; i < 4; ++i) { s += v[i]; s2 += v[i] * v[i]; }
#pragma unroll
    for (int off = 32; off > 0; off >>= 1) {
        s  += __shfl_down(s,  off, 64);
        s2 += __shfl_down(s2, off, 64);
    }
    __shared__ float red[8];
    int wave = tid >> 6;
    if ((tid & 63) == 0) { red[wave] = s; red[wave + 4] = s2; }
    __syncthreads();
    float ts  = red[0] + red[1] + red[2] + red[3];
    float ts2 = red[4] + red[5] + red[6] + red[7];
    float mu  = ts * (1.f / 1024.f);
    float var = ts2 * (1.f / 1024.f) - mu * mu;
    float rstd = rsqrtf(var + 1e-5f);

    float4 gg = *(const float4*)(g + tid * 4);
    float4 bb = *(const float4*)(b + tid * 4);
    float gj[4] = {gg.x, gg.y, gg.z, gg.w};
    float bj[4] = {bb.x, bb.y, bb.z, bb.w};
    s16x4 o4;
#pragma unroll
    for (int j = 0; j < 4; ++j) {
        bf16 ob = f2b((v[j] - mu) * rstd * gj[j] + bj[j]);
        o4[j] = *(short*)&ob;
    }
    *(s16x4*)(out + (size_t)row * C + tid * 4) = o4;
}

// ---------------------------------------------------------------------------
// All six weight transposes (fp32 -> bf16, out[n][k] = in[k][n]) in ONE
// kernel. Flat tile id selects matrix + 32x32 tile.
// ---------------------------------------------------------------------------
__global__ __launch_bounds__(256) void prep_weights(
    const float* __restrict__ Wq, const float* __restrict__ Wk,
    const float* __restrict__ Wv, const float* __restrict__ Wo,
    const float* __restrict__ W1, const float* __restrict__ W2,
    bf16* __restrict__ wqkvt, bf16* __restrict__ wot,
    bf16* __restrict__ w1t, bf16* __restrict__ w2t)
{
    __shared__ float t[32][33];
    int tx = threadIdx.x & 31, ty = threadIdx.x >> 5;
    int id = blockIdx.x;
    const float* in; bf16* out; int in_ld, out_ld, n0, k0;
    if (id < 3072) {
        const float* Ws[3] = {Wq, Wk, Wv};
        int m = id >> 10, r = id & 1023;
        int z = r >> 6, rt = r & 63;
        in = Ws[m] + z * 65536;                       // [1024][64]
        out = wqkvt + (size_t)(m * 1024 + z * 64) * 1024;
        in_ld = 64; out_ld = 1024;
        n0 = (rt & 1) * 32; k0 = (rt >> 1) * 32;
    } else if (id < 4096) {
        int r = id - 3072;
        in = Wo; out = wot; in_ld = 1024; out_ld = 1024;
        n0 = (r & 31) * 32; k0 = (r >> 5) * 32;
    } else if (id < 8192) {
        int r = id - 4096;
        in = W1; out = w1t; in_ld = 4096; out_ld = 1024;
        n0 = (r & 127) * 32; k0 = (r >> 7) * 32;
    } else {
        int r = id - 8192;
        in = W2; out = w2t; in_ld = 1024; out_ld = 4096;
        n0 = (r & 31) * 32; k0 = (r >> 5) * 32;
    }
#pragma unroll
    for (int i = 0; i < 4; ++i)
        t[ty + i * 8][tx] = in[(size_t)(k0 + ty + i * 8) * in_ld + n0 + tx];
    __syncthreads();
#pragma unroll
    for (int i = 0; i < 4; ++i)
        out[(size_t)(n0 + ty + i * 8) * out_ld + k0 + tx] = f2b(t[tx][ty + i * 8]);
}

// ---------------------------------------------------------------------------
// 256x256 MFMA GEMM, plain HIP. 512 thr = 8 waves. BK=32, FOUR LDS buffers
// (128 KB), staging 3 tiles ahead alias-free.
// ONE phase per K-tile (this round): all 12 fragment reads + A&B stage up
// front, ONE counted-vmcnt ladder, ONE barrier pair around 32 MFMA. Halves
// barrier count + vmcnt waits per MFMA vs the R6 2-phase body (which paid
// ~550 cyc/phase of sync overhead per the MfmaUtil 33.5 budget).
// Counted vmcnt (NEVER 0 in steady state): vmcnt(8) => tile t+1 resident
// (12 outstanding -> allow 8 newest = tiles t+2,t+3). Tail: 8 -> 4 -> 0.
// Swizzle: verified 0-conflict scheme.
// VSTORE (QKV only): V-columns (gn>=2048) also store 4-row-packed transposed
// values straight to vt[(b*16+h)*64+d][t] -- fuses the old vt_kernel.
// Requires: M%256==0, N%256==0, K%32==0, K/32>=4, grid %8==0.
// ---------------------------------------------------------------------------
template<bool RELU, bool HAS_BIAS, bool VSTORE, typename OutT>
__global__ __launch_bounds__(512, 2) void gemm8p(
    const bf16* __restrict__ A, int lda,
    const bf16* __restrict__ Bt, int ldb,
    const float* __restrict__ bias,
    OutT* __restrict__ Cm, int ldc,
    bf16* __restrict__ vt, int T,
    int M, int N, int K)
{
    __shared__ short As[4][8192];
    __shared__ short Bs[4][8192];
    int tid = threadIdx.x, wv = tid >> 6, ln = tid & 63;
    int quad = ln >> 4, lane15 = ln & 15;

    // XCD-chunked bijective remap (nwg % 8 == 0)
    int nbn = N >> 8;
    int nwg = gridDim.x;
    int f2 = (blockIdx.x & 7) * (nwg >> 3) + (blockIdx.x >> 3);
    int by = f2 / nbn, bx = f2 % nbn;
    int bm0 = by << 8, bn0 = bx << 8;

    int wr = wv >> 2, wc = wv & 3;     // wave row-half / col-quarter
    const int NT = K >> 5;

    // staging addresses (per thread); linear LDS dest, swizzled source
    int sr = tid >> 2;                                  // row 0..127
    int sc = ((tid & 3) ^ ((sr >> 1) & 3)) * 8;
    const bf16* Ab1 = A  + (size_t)(bm0 + sr) * lda + sc;
    const bf16* Ab2 = A  + (size_t)(bm0 + 128 + sr) * lda + sc;
    const bf16* Bb1 = Bt + (size_t)(bn0 + sr) * ldb + sc;
    const bf16* Bb2 = Bt + (size_t)(bn0 + 128 + sr) * ldb + sc;

#define STAGE_A8(bf_, u_) { \
    load_lds16(Ab1 + (u_) * 32, &As[bf_][wv * 512]); \
    load_lds16(Ab2 + (u_) * 32, &As[bf_][4096 + wv * 512]); }
#define STAGE_B8(bf_, u_) { \
    load_lds16(Bb1 + (u_) * 32, &Bs[bf_][wv * 512]); \
    load_lds16(Bb2 + (u_) * 32, &Bs[bf_][4096 + wv * 512]); }

    f32x4 acc[8][4] = {};                 // 128 VGPRs
    int arow = wr * 128 + lane15;
    int brow = wc * 64 + lane15;
    int sw = (quad ^ ((lane15 >> 1) & 3)) * 8;

    // prologue: stage tiles 0,1,2; wait tile 0 (8 loads stay in flight)
    STAGE_A8(0, 0); STAGE_B8(0, 0);
    STAGE_A8(1, 1); STAGE_B8(1, 1);
    STAGE_A8(2, 2); STAGE_B8(2, 2);
    asm volatile("s_waitcnt vmcnt(8)" ::: "memory");
    __builtin_amdgcn_s_barrier();

    for (int t = 0; t < NT; ++t) {
        int buf = t & 3;
        const short* Al = &As[buf][0];
        const short* Bl = &Bs[buf][0];

        // ---- single phase: all 12 frag reads; stage A&B(t+3); counted wait
        bf16x8 af[8], bfr[4];
#pragma unroll
        for (int mi = 0; mi < 8; ++mi)
            af[mi] = *(const bf16x8*)&Al[(arow + mi * 16) * 32 + sw];
#pragma unroll
        for (int ni = 0; ni < 4; ++ni)
            bfr[ni] = *(const bf16x8*)&Bl[(brow + ni * 16) * 32 + sw];
        if (t + 3 < NT) { STAGE_A8((t + 3) & 3, t + 3); STAGE_B8((t + 3) & 3, t + 3); }
        if (t < NT - 3) {
            asm volatile("s_waitcnt vmcnt(8)" ::: "memory");   // tile t+1 landed
        } else if (t == NT - 3) {
            asm volatile("s_waitcnt vmcnt(4)" ::: "memory");
        } else if (t == NT - 2) {
            asm volatile("s_waitcnt vmcnt(0)" ::: "memory");   // tail only
        }
        __builtin_amdgcn_s_barrier();
        __builtin_amdgcn_s_setprio(1);
#pragma unroll
        for (int mi = 0; mi < 8; ++mi)
#pragma unroll
            for (int ni = 0; ni < 4; ++ni)
                acc[mi][ni] = __builtin_amdgcn_mfma_f32_16x16x32_bf16(
                    af[mi], bfr[ni], acc[mi][ni], 0, 0, 0);
        __builtin_amdgcn_s_setprio(0);
        __builtin_amdgcn_s_barrier();
    }

#undef STAGE_A8
#undef STAGE_B8

    // ---- epilogue (mi -> ni -> r so the 4 r-values of one (mi,ni) are
    //      together for the packed transposed V store)
#pragma unroll
    for (int mi = 0; mi < 8; ++mi) {
        int gm0 = bm0 + wr * 128 + mi * 16 + quad * 4;
#pragma unroll
        for (int ni = 0; ni < 4; ++ni) {
            int gn = bn0 + wc * 64 + ni * 16 + lane15;
            float vv[4];
#pragma unroll
            for (int r = 0; r < 4; ++r) {
                float v = acc[mi][ni][r];
                if (HAS_BIAS) v += bias[gn];
                if (RELU)     v = fmaxf(v, 0.f);
                vv[r] = v;
                stf(Cm + (size_t)(gm0 + r) * ldc + gn, v);
            }
            if (VSTORE && gn >= 2048) {
                // transposed V: vt[((b*16+h)*64+d)][t], 4 consecutive t
                int hd = gn - 2048;                  // h*64 + d
                int bb = gm0 >> 11, t0 = gm0 & 2047; // T = 2048
                u32x2 pk;
                pk[0] = cvt_pk_bf16(vv[0], vv[1]);
                pk[1] = cvt_pk_bf16(vv[2], vv[3]);
                *(u32x2*)&vt[(size_t)(bb * 1024 + hd) * T + t0] = pk;
            }
        }
    }
}

// ---------------------------------------------------------------------------
// MFMA GEMM: C[M,N] = A[M,K] @ B[K,N], B given TRANSPOSED (Bt[n][k]).
// 128x128 tile, 256 thr = 4 waves, templated BK (32 or 64). Double-buffered
// LDS, stage-before-compute, one __syncthreads per K-step. Used for the
// N=1024 GEMMs (Wo, FFN2) where 256-wide col tiles would underfill the grid.
// ---------------------------------------------------------------------------
template<int BK, bool RELU, bool HAS_BIAS, bool HAS_RES, typename ResT, typename OutT>
__global__ __launch_bounds__(256) void gemm_bt(
    const bf16* __restrict__ A, int lda,
    const bf16* __restrict__ Bt, int ldb,
    const float* __restrict__ bias,
    const ResT* __restrict__ res, int ldr,
    OutT* __restrict__ Cm, int ldc,
    int M, int N, int K)
{
    __shared__ short As[2][128 * BK];
    __shared__ short Bs[2][128 * BK];
    int tid = threadIdx.x, wv = tid >> 6, ln = tid & 63;

    int f = blockIdx.x + blockIdx.y * gridDim.x;
    int nby = gridDim.y;
    int by = f % nby, bx = f / nby;
    int bm0 = by * 128, bn0 = bx * 128;

    int wm = (wv & 1) * 64, wn = (wv >> 1) * 64;
    int quad = ln >> 4, lane15 = ln & 15;

    f32x4 acc[4][4] = {};

    const bf16* Ab = A + (size_t)bm0 * lda;
    const bf16* Bb = Bt + (size_t)bn0 * ldb;

    auto stage = [&](int buf, int kk) {
        if constexpr (BK == 32) {
            int srow = ln >> 2;
            int scol = (((ln & 3) ^ ((ln >> 3) & 3)) * 8);
#pragma unroll
            for (int i = 0; i < 2; ++i) {
                int ch = wv + i * 4;
                load_lds16(Ab + (size_t)(ch * 16 + srow) * lda + kk + scol,
                           &As[buf][ch * 16 * 32]);
                load_lds16(Bb + (size_t)(ch * 16 + srow) * ldb + kk + scol,
                           &Bs[buf][ch * 16 * 32]);
            }
        } else {
            int srow = ln >> 3;
            int scol = ((ln & 7) ^ srow) * 8;
#pragma unroll
            for (int i = 0; i < 4; ++i) {
                int r0 = i * 32 + wv * 8;
                load_lds16(Ab + (size_t)(r0 + srow) * lda + kk + scol,
                           &As[buf][r0 * 64]);
                load_lds16(Bb + (size_t)(r0 + srow) * ldb + kk + scol,
                           &Bs[buf][r0 * 64]);
            }
        }
    };

    stage(0, 0);
    __syncthreads();

    int cur = 0;
    for (int k0 = 0; k0 < K; k0 += BK) {
        if (k0 + BK < K) stage(cur ^ 1, k0 + BK);
        if constexpr (BK == 32) {
            int sw = (quad ^ ((lane15 >> 1) & 3)) * 8;
            bf16x8 af[4], bfr[4];
#pragma unroll
            for (int mi = 0; mi < 4; ++mi)
                af[mi] = *(const bf16x8*)&As[cur][(wm + mi * 16 + lane15) * 32 + sw];
#pragma unroll
            for (int ni = 0; ni < 4; ++ni)
                bfr[ni] = *(const bf16x8*)&Bs[cur][(wn + ni * 16 + lane15) * 32 + sw];
#pragma unroll
            for (int mi = 0; mi < 4; ++mi)
#pragma unroll
                for (int ni = 0; ni < 4; ++ni)
                    acc[mi][ni] = __builtin_amdgcn_mfma_f32_16x16x32_bf16(
                        af[mi], bfr[ni], acc[mi][ni], 0, 0, 0);
        } else {
#pragma unroll
            for (int ks = 0; ks < 2; ++ks) {
                int sw = (((ks * 4 + quad) ^ (lane15 & 7)) * 8);
                bf16x8 af[4], bfr[4];
#pragma unroll
                for (int mi = 0; mi < 4; ++mi)
                    af[mi] = *(const bf16x8*)&As[cur][(wm + mi * 16 + lane15) * 64 + sw];
#pragma unroll
                for (int ni = 0; ni < 4; ++ni)
                    bfr[ni] = *(const bf16x8*)&Bs[cur][(wn + ni * 16 + lane15) * 64 + sw];
#pragma unroll
                for (int mi = 0; mi < 4; ++mi)
#pragma unroll
                    for (int ni = 0; ni < 4; ++ni)
                        acc[mi][ni] = __builtin_amdgcn_mfma_f32_16x16x32_bf16(
                            af[mi], bfr[ni], acc[mi][ni], 0, 0, 0);
            }
        }
        __syncthreads();
        cur ^= 1;
    }

#pragma unroll
    for (int mi = 0; mi < 4; ++mi) {
#pragma unroll
        for (int r = 0; r < 4; ++r) {
            int gm = bm0 + wm + mi * 16 + quad * 4 + r;
#pragma unroll
            for (int ni = 0; ni < 4; ++ni) {
                int gn = bn0 + wn + ni * 16 + lane15;
                float v = acc[mi][ni][r];
                if (HAS_BIAS) v += bias[gn];
                if (HAS_RES)  v += ldf(res + (size_t)gm * ldr + gn);
                if (RELU)     v = fmaxf(v, 0.f);
                stf(Cm + (size_t)gm * ldc + gn, v);
            }
        }
    }
}

// ---------------------------------------------------------------------------
// 32x32x16 attention tile step (R11-verified). S^T = mfma(K, Q): lane holds
// S^T[key = (r&3)+8*(r>>2)+4*hi + ts*32][q = lane&31]. Constant-shift
// softmax (exp2 domain). P^T B-fragment for PV built IN-REGISTER:
// 4 cvt_pk + 2 permlane32_swap (builtin) per 16-key slice. No P LDS traffic.
// DUAL: shared kf/vf reads feed both q-tiles; mask applies to b only.
// ---------------------------------------------------------------------------
template<bool DUAL>
__device__ __forceinline__ void attn_tile32(
    const short* __restrict__ Ks, const short* __restrict__ Vs,
    const bf16x8* qfa, const bf16x8* qfb,
    f32x16* oa, f32x16* ob, float& lra, float& lrb,
    int kb, int qmina, int qminb, int l31, int hi, int l7)
{
    const float scale2 = 0.18033688011112042f;   // (1/8) * log2(e)
    f32x16 sa[2] = {};
    f32x16 sb[2] = {};

    __builtin_amdgcn_s_setprio(1);
#pragma unroll
    for (int ts = 0; ts < 2; ++ts) {
#pragma unroll
        for (int ks = 0; ks < 4; ++ks) {
            bf16x8 kf = *(const bf16x8*)&Ks[(ts * 32 + l31) * 64 + (((ks * 2 + hi) ^ l7) * 8)];
            sa[ts] = __builtin_amdgcn_mfma_f32_32x32x16_bf16(kf, qfa[ks], sa[ts], 0, 0, 0);
            if (DUAL)
                sb[ts] = __builtin_amdgcn_mfma_f32_32x32x16_bf16(kf, qfb[ks], sb[ts], 0, 0, 0);
        }
    }
    __builtin_amdgcn_s_setprio(0);

    // causal mask (fused path masks b; single path masks a)
    int qmin = DUAL ? qminb : qmina;
    if (kb + 63 > qmin) {
        int qcap = qmin + l31;
#pragma unroll
        for (int ts = 0; ts < 2; ++ts)
#pragma unroll
            for (int r = 0; r < 16; ++r) {
                int key = kb + ts * 32 + (r & 3) + 8 * (r >> 2) + 4 * hi;
                if (key > qcap) {
                    if (DUAL) sb[ts][r] = -3e38f; else sa[ts][r] = -3e38f;
                }
            }
    }

    // exp2 in place + row-partial sums (lane holds 32 of 64 keys for q=l31)
    float psa = 0.f, psb = 0.f;
#pragma unroll
    for (int ts = 0; ts < 2; ++ts)
#pragma unroll
        for (int r = 0; r < 16; ++r) {
            float va = exp2f(sa[ts][r] * scale2);
            sa[ts][r] = va; psa += va;
            if (DUAL) {
                float vb = exp2f(sb[ts][r] * scale2);
                sb[ts][r] = vb; psb += vb;
            }
        }
    lra += psa;
    if (DUAL) lrb += psb;

    // PV: per 16-key slice s build P^T frag in-register, MFMA vs V^T
    __builtin_amdgcn_s_setprio(1);
#pragma unroll
    for (int s = 0; s < 4; ++s) {
        const int ts = s >> 1, q0 = (s & 1) * 8;
        unsigned a0 = cvt_pk_bf16(sa[ts][q0 + 0], sa[ts][q0 + 1]);
        unsigned a1 = cvt_pk_bf16(sa[ts][q0 + 2], sa[ts][q0 + 3]);
        unsigned a2 = cvt_pk_bf16(sa[ts][q0 + 4], sa[ts][q0 + 5]);
        unsigned a3 = cvt_pk_bf16(sa[ts][q0 + 6], sa[ts][q0 + 7]);
        u32x2 s02 = __builtin_amdgcn_permlane32_swap(a0, a2, false, false);
        u32x2 s13 = __builtin_amdgcn_permlane32_swap(a1, a3, false, false);
        u32x4 fa = {s02[0], s13[0], s02[1], s13[1]};
        bf16x8 pfa = *(bf16x8*)&fa;
        bf16x8 pfb;
        if (DUAL) {
            unsigned b0 = cvt_pk_bf16(sb[ts][q0 + 0], sb[ts][q0 + 1]);
            unsigned b1 = cvt_pk_bf16(sb[ts][q0 + 2], sb[ts][q0 + 3]);
            unsigned b2 = cvt_pk_bf16(sb[ts][q0 + 4], sb[ts][q0 + 5]);
            unsigned b3 = cvt_pk_bf16(sb[ts][q0 + 6], sb[ts][q0 + 7]);
            u32x2 t02 = __builtin_amdgcn_permlane32_swap(b0, b2, false, false);
            u32x2 t13 = __builtin_amdgcn_permlane32_swap(b1, b3, false, false);
            u32x4 fb = {t02[0], t13[0], t02[1], t13[1]};
            pfb = *(bf16x8*)&fb;
        }
#pragma unroll
        for (int dt = 0; dt < 2; ++dt) {
            bf16x8 vf = *(const bf16x8*)&Vs[(dt * 32 + l31) * 64 + (((s * 2 + hi) ^ l7) * 8)];
            oa[dt] = __builtin_amdgcn_mfma_f32_32x32x16_bf16(vf, pfa, oa[dt], 0, 0, 0);
            if (DUAL)
                ob[dt] = __builtin_amdgcn_mfma_f32_32x32x16_bf16(vf, pfb, ob[dt], 0, 0, 0);
        }
    }
    __builtin_amdgcn_s_setprio(0);
}

// ---------------------------------------------------------------------------
// MFMA causal flash attention, 32x32x16 form, 512 thr = 8 waves x 32 q-rows
// (256-row q-tile). CAUSAL-BALANCED DUAL Q-TILE: block bx processes q-tiles
// (7-bx, bx) in ONE k-loop sharing K/V staging AND fragment reads.
// ---------------------------------------------------------------------------
__global__ __launch_bounds__(512, 2) void attn_kernel(
    const bf16* __restrict__ qkv, const bf16* __restrict__ vt,
    bf16* __restrict__ o, int T)
{
    const int LDQ = 3072;
    int bx = blockIdx.x;             // 0..3
    int qta = 7 - bx;                // heavy q-tile (256 rows)
    int qtb = bx;                    // light q-tile
    int h = blockIdx.y, b = blockIdx.z;
    int tid = threadIdx.x, wv = tid >> 6, ln = tid & 63;
    int l31 = ln & 31, hi = ln >> 5, l7 = ln & 7;

    __shared__ short KV[2][2][64 * 64];   // [buf][0=K [key][d], 1=V [d][key]]

    int lr = ln >> 3;                     // staging row within 8-row chunk
    int lc = ((ln & 7) ^ lr) * 8;         // swizzled source col offset

    const bf16* kbase = qkv + (size_t)(b * T) * LDQ + 1024 + h * 64;
    const bf16* vbase = vt + (size_t)((b * 16 + h) * 64) * T;

    // ---- Q fragments straight from global (once per block)
    bf16x8 qfa[4], qfb[4];
    {
        const bf16* qa = qkv + (size_t)(b * T + qta * 256 + wv * 32 + l31) * LDQ + h * 64 + hi * 8;
        const bf16* qb = qkv + (size_t)(b * T + qtb * 256 + wv * 32 + l31) * LDQ + h * 64 + hi * 8;
#pragma unroll
        for (int ks = 0; ks < 4; ++ks) {
            qfa[ks] = *(const bf16x8*)(qa + ks * 16);
            qfb[ks] = *(const bf16x8*)(qb + ks * 16);
        }
    }

    f32x16 oa[2] = {}, ob[2] = {};
    float lra = 0.f, lrb = 0.f;
    int qmina = qta * 256 + wv * 32;
    int qminb = qtb * 256 + wv * 32;
    int ntiles = (qta + 1) * 4;

    // stage tile 0 into buf 0 (wave wv stages rows wv*8..wv*8+7)
    const bf16* kp = kbase + (size_t)(wv * 8 + lr) * LDQ + lc;
    const bf16* vp = vbase + (size_t)(wv * 8 + lr) * T + lc;
    load_lds16(kp, &KV[0][0][wv * 8 * 64]);
    load_lds16(vp, &KV[0][1][wv * 8 * 64]);

    for (int kt = 0; kt < ntiles; ++kt) {
        __syncthreads();   // tile kt published (barrier drains vmcnt)
        if (kt + 1 < ntiles) {
            int nb = (kt + 1) & 1;
            kp += 64 * LDQ;
            vp += 64;
            load_lds16(kp, &KV[nb][0][wv * 8 * 64]);
            load_lds16(vp, &KV[nb][1][wv * 8 * 64]);
        }
        const short* Ks = &KV[kt & 1][0][0];
        const short* Vs = &KV[kt & 1][1][0];
        int kb = kt * 64;

        if (kb <= qminb + 31)
            attn_tile32<true>(Ks, Vs, qfa, qfb, oa, ob, lra, lrb,
                              kb, qmina, qminb, l31, hi, l7);
        else if (kb <= qmina + 31)
            attn_tile32<false>(Ks, Vs, qfa, qfb, oa, ob, lra, lrb,
                               kb, qmina, qminb, l31, hi, l7);
    }

    // ---- epilogue: cross-half l reduce + store. O^T reg layout:
    // value (d_local = (r&3)+8*(r>>2)+4*hi + dt*32, q = l31).
    lra += __shfl_xor(lra, 32, 64);
    float inva = 1.f / lra;
    size_t rowa = (size_t)(b * T + qta * 256 + wv * 32 + l31);
#pragma unroll
    for (int dt = 0; dt < 2; ++dt)
#pragma unroll
        for (int rq = 0; rq < 4; ++rq) {
            u32x2 ou;
            ou[0] = cvt_pk_bf16(oa[dt][rq * 4 + 0] * inva, oa[dt][rq * 4 + 1] * inva);
            ou[1] = cvt_pk_bf16(oa[dt][rq * 4 + 2] * inva, oa[dt][rq * 4 + 3] * inva);
            *(u32x2*)&o[rowa * 1024 + h * 64 + dt * 32 + rq * 8 + hi * 4] = ou;
        }

    lrb += __shfl_xor(lrb, 32, 64);
    float invb = 1.f / lrb;
    size_t rowb = (size_t)(b * T + qtb * 256 + wv * 32 + l31);
#pragma unroll
    for (int dt = 0; dt < 2; ++dt)
#pragma unroll
        for (int rq = 0; rq < 4; ++rq) {
            u32x2 ou;
            ou[0] = cvt_pk_bf16(ob[dt][rq * 4 + 0] * invb, ob[dt][rq * 4 + 1] * invb);
            ou[1] = cvt_pk_bf16(ob[dt][rq * 4 + 2] * invb, ob[dt][rq * 4 + 3] * invb);
            *(u32x2*)&o[rowb * 1024 + h * 64 + dt * 32 + rq * 8 + hi * 4] = ou;
        }
}

// ---------------------------------------------------------------------------
extern "C" void kernel_launch(void* const* d_in, const int* in_sizes, int n_in,
                              void* d_out, int out_size, void* d_ws, size_t ws_size,
                              hipStream_t stream)
{
    (void)in_sizes; (void)n_in; (void)out_size; (void)ws_size;
    const float* x   = (const float*)d_in[0];
    const float* Wq  = (const float*)d_in[1];
    const float* Wk  = (const float*)d_in[2];
    const float* Wv  = (const float*)d_in[3];
    const float* Wo  = (const float*)d_in[4];
    const float* bo  = (const float*)d_in[5];
    const float* g1  = (const float*)d_in[6];
    const float* be1 = (const float*)d_in[7];
    const float* g2  = (const float*)d_in[8];
    const float* be2 = (const float*)d_in[9];
    const float* W1  = (const float*)d_in[10];
    const float* b1  = (const float*)d_in[11];
    const float* W2  = (const float*)d_in[12];
    const float* b2  = (const float*)d_in[13];

    const int T = 2048, M = 4 * T;  // 8192 rows
    const size_t MB = 1ull << 20;
    char* ws = (char*)d_ws;

    // workspace map (128 MB, live-range overlays):
    bf16*  xn    = (bf16*)(ws + 0 * MB);     // 16 MB; later: attnb; later: hb
    bf16*  qkv   = (bf16*)(ws + 16 * MB);    // 48 MB [M][3072]; later: hb tail
    bf16*  vt    = (bf16*)(ws + 64 * MB);    // 16 MB [b*16+h][64][T]
    bf16*  wqkvt = (bf16*)(ws + 80 * MB);    //  6 MB [3072][1024]; later: x1b
    bf16*  x1b   = (bf16*)(ws + 80 * MB);    // 16 MB [M][1024] bf16 residual
    bf16*  wot   = (bf16*)(ws + 96 * MB);    //  2 MB; later: xn2
    bf16*  xn2   = (bf16*)(ws + 96 * MB);    // 16 MB
    bf16*  w1t   = (bf16*)(ws + 112 * MB);   //  8 MB [4096][1024]
    bf16*  w2t   = (bf16*)(ws + 120 * MB);   //  8 MB [1024][4096]
    bf16*  attnb = (bf16*)(ws + 0 * MB);
    bf16*  hb    = (bf16*)(ws + 0 * MB);     // 64 MB [M][4096]

    dim3 blk(256);

    prep_weights<<<12288, blk, 0, stream>>>(Wq, Wk, Wv, Wo, W1, W2,
                                            wqkvt, wot, w1t, w2t);

    ln_kernel<float><<<M, blk, 0, stream>>>(x, g1, be1, xn);

    // QKV: 256^2 single-phase pipelined, grid 384; V^T fused into epilogue
    gemm8p<false, false, true, bf16><<<dim3(384), dim3(512), 0, stream>>>(
        xn, 1024, wqkvt, 1024, nullptr, qkv, 3072, vt, T, M, 3072, 1024);

    attn_kernel<<<dim3(4, 16, 4), dim3(512), 0, stream>>>(qkv, vt, attnb, T);

    gemm_bt<32, false, true, true, float, bf16><<<dim3(8, 64), blk, 0, stream>>>(
        attnb, 1024, wot, 1024, bo, x, 1024, x1b, 1024, M, 1024, 1024);

    ln_kernel<bf16><<<M, blk, 0, stream>>>(x1b, g2, be2, xn2);

    // FFN1: 256^2 single-phase pipelined, grid 512
    gemm8p<true, true, false, bf16><<<dim3(512), dim3(512), 0, stream>>>(
        xn2, 1024, w1t, 1024, b1, hb, 4096, nullptr, T, M, 4096, 1024);

    gemm_bt<64, false, true, true, bf16, float><<<dim3(8, 64), blk, 0, stream>>>(
        hb, 4096, w2t, 4096, b2, x1b, 1024, (float*)d_out, 1024, M, 1024, 4096);
}